// Round 2
// 305.067 us; speedup vs baseline: 1.0869x; 1.0869x over previous
//
#include <hip/hip_runtime.h>
#include <hip/hip_bf16.h>

// ---------------------------------------------------------------------------
// GCN 2-layer forward on MI355X.
// Round 12: R11 fix — out_size is FLOAT ELEMENTS (G = out_size/64, as in the
// passing R10 kernel), and memset must cover out_size*4 bytes. R11's G=/256
// left graphs 32..127 with gcnt=0 (sum instead of mean -> absmax 201) and
// 3/4 of out un-zeroed. Kernels unchanged from R11:
//   (1) h1 stored fp8-e4m3 -> spmm1 gathers one 128B line/edge, 2 edges/wave;
//   (2) pool fused into spmm2 via block-reduced f32 atomics;
//   (3) gemm1 epilogue packs fp8 with uint2 stores; permutation absorbed
//       into b1 gather, x2n layout, gemm2 W-row indexing.
// ---------------------------------------------------------------------------

#define NPP_SHIFT 9
#define NPP 512
#define MAXP 256
#define NB 512

typedef __attribute__((ext_vector_type(8))) short frag8;
typedef __attribute__((ext_vector_type(4))) float f32x4;
typedef __attribute__((ext_vector_type(2))) float v2f;

// ---- Pass A: per-block histograms of src/dst partitions + graph counts --
__launch_bounds__(256)
__global__ void passA_count(const int* __restrict__ src, const int* __restrict__ dst,
                            int E, int P, int* __restrict__ counts_src,
                            int* __restrict__ counts_dst,
                            const int* __restrict__ gids, int N, int G,
                            int* __restrict__ gcnt) {
    __shared__ int h1[MAXP], h2[MAXP], h3[MAXP];
    int tid = threadIdx.x;
    for (int i = tid; i < MAXP; i += 256) { h1[i] = 0; h2[i] = 0; h3[i] = 0; }
    __syncthreads();
    int per_block = (E + NB - 1) / NB;
    int e0 = blockIdx.x * per_block;
    int e1 = min(e0 + per_block, E);
    for (int e = e0 + tid; e < e1; e += 256) {
        atomicAdd(&h1[src[e] >> NPP_SHIFT], 1);
        atomicAdd(&h2[dst[e] >> NPP_SHIFT], 1);
    }
    int npb = (N + NB - 1) / NB;
    int n0 = blockIdx.x * npb;
    int n1 = min(n0 + npb, N);
    for (int i = n0 + tid; i < n1; i += 256) atomicAdd(&h3[gids[i]], 1);
    __syncthreads();
    for (int i = tid; i < P; i += 256) {
        counts_src[(size_t)blockIdx.x * P + i] = h1[i];
        counts_dst[(size_t)blockIdx.x * P + i] = h2[i];
    }
    for (int i = tid; i < G; i += 256)
        if (h3[i]) atomicAdd(&gcnt[i], h3[i]);
}

// ---- Pass B: exclusive scan across blocks for each (stream, partition) --
__launch_bounds__(1024)
__global__ void scanB(const int* __restrict__ counts, int* __restrict__ offs,
                      int* __restrict__ ptot, int P) {
    __shared__ int s[1024];
    int tid = threadIdx.x;
    int p = blockIdx.x % P;
    int st = blockIdx.x / P;
    const int* c = counts + (size_t)st * NB * P;
    int v = (tid < NB) ? c[(size_t)tid * P + p] : 0;
    s[tid] = v;
    __syncthreads();
    for (int off = 1; off < 1024; off <<= 1) {
        int t = (tid >= off) ? s[tid - off] : 0;
        __syncthreads();
        s[tid] += t;
        __syncthreads();
    }
    if (tid < NB) offs[(size_t)st * NB * P + (size_t)tid * P + p] = s[tid] - v;
    if (tid == 1023) ptot[st * P + p] = s[1023];
}

// ---- Pass C: scatter into partition-bucketed buffers (LDS cursors) ------
__launch_bounds__(256)
__global__ void passC_scatter(const int* __restrict__ src, const int* __restrict__ dst,
                              int E, int P, const int* __restrict__ offs,
                              const int* __restrict__ ptot, int* __restrict__ pbase,
                              int* __restrict__ ebuf_src, int2* __restrict__ ebuf_dst) {
    __shared__ int cur1[MAXP], cur2[MAXP], sc[256];
    int tid = threadIdx.x;
    int v = (tid < P) ? ptot[tid] : 0;
    sc[tid] = v;
    __syncthreads();
    for (int off = 1; off < 256; off <<= 1) {
        int t = (tid >= off) ? sc[tid - off] : 0;
        __syncthreads();
        sc[tid] += t;
        __syncthreads();
    }
    int base0 = sc[tid] - v;
    if (tid < P) {
        cur1[tid] = base0 + offs[(size_t)blockIdx.x * P + tid];
        if (blockIdx.x == 0) pbase[tid] = base0;
    }
    __syncthreads();
    v = (tid < P) ? ptot[P + tid] : 0;
    sc[tid] = v;
    __syncthreads();
    for (int off = 1; off < 256; off <<= 1) {
        int t = (tid >= off) ? sc[tid - off] : 0;
        __syncthreads();
        sc[tid] += t;
        __syncthreads();
    }
    int base1 = sc[tid] - v;
    if (tid < P) {
        cur2[tid] = base1 + offs[(size_t)NB * P + (size_t)blockIdx.x * P + tid];
        if (blockIdx.x == 0) pbase[P + tid] = base1;
    }
    __syncthreads();
    int per_block = (E + NB - 1) / NB;
    int e0 = blockIdx.x * per_block;
    int e1 = min(e0 + per_block, E);
    for (int e = e0 + tid; e < e1; e += 256) {
        int s = src[e];
        int d = dst[e];
        int pos1 = atomicAdd(&cur1[s >> NPP_SHIFT], 1);
        ebuf_src[pos1] = s;
        int pos2 = atomicAdd(&cur2[d >> NPP_SHIFT], 1);
        ebuf_dst[pos2] = make_int2(d, s);
    }
}

// ---- Pass D: per-partition degree/norm/row_start/csr build --------------
__launch_bounds__(512)
__global__ void passD_build(const int* __restrict__ ebuf_src, const int2* __restrict__ ebuf_dst,
                            const int* __restrict__ ptot, const int* __restrict__ pbase,
                            float* __restrict__ norm_src, int* __restrict__ row_start,
                            int* __restrict__ csr_src, int N, int E, int P) {
    __shared__ int hs[NPP], hd[NPP], sc[NPP];
    int tid = threadIdx.x;
    int p = blockIdx.x;
    int node_lo = p << NPP_SHIFT;
    int nl = min(NPP, N - node_lo);
    hs[tid] = 0;
    hd[tid] = 0;
    __syncthreads();
    int nsrc = ptot[p];
    int base_s = pbase[p];
    for (int i = tid; i < nsrc; i += 512)
        atomicAdd(&hs[ebuf_src[base_s + i] - node_lo], 1);
    int ndst = ptot[P + p];
    int base_d = pbase[P + p];
    for (int i = tid; i < ndst; i += 512)
        atomicAdd(&hd[ebuf_dst[base_d + i].x - node_lo], 1);
    __syncthreads();
    if (tid < nl) norm_src[node_lo + tid] = rsqrtf((float)max(hs[tid], 1));
    int myh = hd[tid];
    sc[tid] = myh;
    __syncthreads();
    for (int off = 1; off < 512; off <<= 1) {
        int t = (tid >= off) ? sc[tid - off] : 0;
        __syncthreads();
        sc[tid] += t;
        __syncthreads();
    }
    int row0 = base_d + sc[tid] - myh;
    if (tid < nl) row_start[node_lo + tid] = row0;
    if (p == P - 1 && tid == 0) row_start[N] = E;
    __syncthreads();
    hd[tid] = row0;  // reuse as cursor
    __syncthreads();
    for (int i = tid; i < ndst; i += 512) {
        int2 r = ebuf_dst[base_d + i];
        int pos = atomicAdd(&hd[r.x - node_lo], 1);
        csr_src[pos] = r.y;
    }
}

// ---- MFMA GEMM: out[n x COLS] = A[n x 128] @ W[128 x COLS] --------------
// FP8OUT (COLS=128 only): writes fp8 rows in permuted order:
//   u32 slot s, byte c  <->  feature 64*(s&1) + 16*c + (s>>1)
// PERM: LDS W row k sources w[feat(k)] to absorb the permuted A layout.
template <int COLS, bool BF16IN, bool PERM, bool FP8OUT>
__launch_bounds__(256)
__global__ void gemm_mfma(const void* __restrict__ xin, const float* __restrict__ w,
                          const float* __restrict__ norm,
                          void* __restrict__ out, int n) {
    constexpr int NT = COLS / 16;
    __shared__ short wlds[4 * NT * 64 * 8];
    const int tid = threadIdx.x;
    for (int i = tid; i < 128 * COLS / 4; i += 256) {
        int k = (i * 4) / COLS;
        int n0 = (i * 4) % COLS;
        float4 wv;
        if constexpr (PERM) {
            int ksrc = 64 * ((k >> 2) & 1) + 16 * (k & 3) + (k >> 3);
            wv = *reinterpret_cast<const float4*>(w + (size_t)ksrc * COLS + n0);
        } else {
            wv = reinterpret_cast<const float4*>(w)[i];
        }
        int c = k >> 5, q = (k >> 3) & 3, j = k & 7;
        float vals[4] = {wv.x, wv.y, wv.z, wv.w};
#pragma unroll
        for (int u = 0; u < 4; ++u) {
            int nn = n0 + u;
            int t = nn >> 4;
            int ln = (q << 4) | (nn & 15);
            union { __hip_bfloat16 b; short s; } cv;
            cv.b = __float2bfloat16(vals[u]);
            wlds[(((c * NT + t) << 6) | ln) * 8 + j] = cv.s;
        }
    }
    __syncthreads();

    const int lane = tid & 63;
    const int wid = tid >> 6;
    const int m = lane & 15;
    const int q = lane >> 4;
    const int ntiles = (n + 15) >> 4;
    const frag8* wfr = reinterpret_cast<const frag8*>(wlds);

    for (int wt = blockIdx.x * 4 + wid; wt < ntiles; wt += gridDim.x * 4) {
        const int row = (wt << 4) + m;
        frag8 af[4];
        if (row < n) {
            if constexpr (BF16IN) {
                const frag8* xp = reinterpret_cast<const frag8*>(
                    (const __hip_bfloat16*)xin + (size_t)row * 128);
#pragma unroll
                for (int c = 0; c < 4; ++c) af[c] = xp[c * 4 + q];
            } else {
                const float* xp = (const float*)xin + (size_t)row * 128;
                float nm = norm[row];
#pragma unroll
                for (int c = 0; c < 4; ++c) {
                    int base = c * 32 + q * 8;
                    float4 v0 = *reinterpret_cast<const float4*>(xp + base);
                    float4 v1 = *reinterpret_cast<const float4*>(xp + base + 4);
                    union { frag8 f; short s[8]; } a;
                    union { __hip_bfloat16 b; short s; } cv;
                    cv.b = __float2bfloat16(v0.x * nm); a.s[0] = cv.s;
                    cv.b = __float2bfloat16(v0.y * nm); a.s[1] = cv.s;
                    cv.b = __float2bfloat16(v0.z * nm); a.s[2] = cv.s;
                    cv.b = __float2bfloat16(v0.w * nm); a.s[3] = cv.s;
                    cv.b = __float2bfloat16(v1.x * nm); a.s[4] = cv.s;
                    cv.b = __float2bfloat16(v1.y * nm); a.s[5] = cv.s;
                    cv.b = __float2bfloat16(v1.z * nm); a.s[6] = cv.s;
                    cv.b = __float2bfloat16(v1.w * nm); a.s[7] = cv.s;
                    af[c] = a.f;
                }
            }
        } else {
#pragma unroll
            for (int c = 0; c < 4; ++c) af[c] = frag8{0, 0, 0, 0, 0, 0, 0, 0};
        }
        f32x4 acc[NT] = {};
#pragma unroll
        for (int c = 0; c < 4; ++c)
#pragma unroll
            for (int t = 0; t < NT; ++t)
                acc[t] = __builtin_amdgcn_mfma_f32_16x16x32_bf16(
                    af[c], wfr[(c * NT + t) * 64 + lane], acc[t], 0, 0, 0);
#pragma unroll
        for (int r = 0; r < 4; ++r) {
            int grow = (wt << 4) + q * 4 + r;
            if (grow < n) {
                if constexpr (FP8OUT) {
                    // pack 8 feats {16t+m} into 2 u32: slot 2m (t=0..3), 2m+1 (t=4..7)
                    uint w0 = 0, w1 = 0;
                    w0 = (uint)__builtin_amdgcn_cvt_pk_fp8_f32(acc[0][r], acc[1][r], (int)w0, false);
                    w0 = (uint)__builtin_amdgcn_cvt_pk_fp8_f32(acc[2][r], acc[3][r], (int)w0, true);
                    w1 = (uint)__builtin_amdgcn_cvt_pk_fp8_f32(acc[4][r], acc[5][r], (int)w1, false);
                    w1 = (uint)__builtin_amdgcn_cvt_pk_fp8_f32(acc[6][r], acc[7][r], (int)w1, true);
                    reinterpret_cast<uint2*>(out)[(size_t)grow * 16 + m] = make_uint2(w0, w1);
                } else {
                    __hip_bfloat16* ob = reinterpret_cast<__hip_bfloat16*>(out);
#pragma unroll
                    for (int t = 0; t < NT; ++t)
                        ob[(size_t)grow * COLS + t * 16 + m] = __float2bfloat16(acc[t][r]);
                }
            }
        }
    }
}

// ---- SpMM layer 1: wave per dst node, 2 edges/wave, fp8 gathers ---------
// h1 row = 32 u32 (128B, one line). lane: a=lane>>5 edge parity, s=lane&31 slot.
// Accumulates 4 feats/lane (bytes of its u32), combines halves via shfl_xor(32),
// writes x2n bf16 in the SAME permuted position order (p=4s+c).
__launch_bounds__(256)
__global__ void spmm1_kernel(const uint* __restrict__ h1,
                             const int* __restrict__ row_start,
                             const int* __restrict__ csr_src,
                             const float* __restrict__ b1,
                             const float* __restrict__ norm_src,
                             uint2* __restrict__ x2n, int n) {
    int gw = (blockIdx.x * blockDim.x + threadIdx.x) >> 6;
    int lane = threadIdx.x & 63;
    if (gw >= n) return;
    int e0 = row_start[gw];
    int e1 = row_start[gw + 1];
    int a = lane >> 5;
    int s = lane & 31;
    float acc0 = 0.f, acc1 = 0.f, acc2 = 0.f, acc3 = 0.f;
    int e = e0;
    for (; e + 16 <= e1; e += 16) {
        uint v[8];
#pragma unroll
        for (int j = 0; j < 8; ++j) {
            int cs = csr_src[e + 2 * j + a];
            v[j] = h1[(size_t)cs * 32 + s];
        }
#pragma unroll
        for (int j = 0; j < 8; ++j) {
            v2f lo = __builtin_amdgcn_cvt_pk_f32_fp8((int)v[j], false);
            v2f hi = __builtin_amdgcn_cvt_pk_f32_fp8((int)v[j], true);
            acc0 += lo[0]; acc1 += lo[1]; acc2 += hi[0]; acc3 += hi[1];
        }
    }
    if (e < e1) {  // masked tail batch (covers up to 15 edges); fp8 0x00 == 0.0f
        uint v[8];
#pragma unroll
        for (int j = 0; j < 8; ++j) {
            int idx = e + 2 * j + a;
            int cidx = min(idx, e1 - 1);
            int cs = csr_src[cidx];
            uint vv = h1[(size_t)cs * 32 + s];
            v[j] = (idx < e1) ? vv : 0u;
        }
#pragma unroll
        for (int j = 0; j < 8; ++j) {
            v2f lo = __builtin_amdgcn_cvt_pk_f32_fp8((int)v[j], false);
            v2f hi = __builtin_amdgcn_cvt_pk_f32_fp8((int)v[j], true);
            acc0 += lo[0]; acc1 += lo[1]; acc2 += hi[0]; acc3 += hi[1];
        }
    }
    acc0 += __shfl_xor(acc0, 32);
    acc1 += __shfl_xor(acc1, 32);
    acc2 += __shfl_xor(acc2, 32);
    acc3 += __shfl_xor(acc3, 32);
    if (a == 0) {
        float nd = rsqrtf((float)max(e1 - e0, 1));
        float ns = norm_src[gw];
        int m2 = s >> 1;
        int a2 = (s & 1) << 6;
        float f0 = fmaxf(fmaf(acc0, nd, b1[a2 + m2]), 0.f) * ns;
        float f1 = fmaxf(fmaf(acc1, nd, b1[a2 + 16 + m2]), 0.f) * ns;
        float f2 = fmaxf(fmaf(acc2, nd, b1[a2 + 32 + m2]), 0.f) * ns;
        float f3 = fmaxf(fmaf(acc3, nd, b1[a2 + 48 + m2]), 0.f) * ns;
        union { __hip_bfloat16 b; ushort u; } c0, c1, c2, c3;
        c0.b = __float2bfloat16(f0);
        c1.b = __float2bfloat16(f1);
        c2.b = __float2bfloat16(f2);
        c3.b = __float2bfloat16(f3);
        uint w0 = (uint)c0.u | ((uint)c1.u << 16);
        uint w1 = (uint)c2.u | ((uint)c3.u << 16);
        x2n[(size_t)gw * 32 + s] = make_uint2(w0, w1);
    }
}

// ---- SpMM layer 2 + fused mean-pool: bf16 gathers, block-reduced atomics -
__launch_bounds__(256)
__global__ void spmm2_kernel(const __hip_bfloat16* __restrict__ h,
                             const int* __restrict__ row_start,
                             const int* __restrict__ csr_src,
                             const float* __restrict__ b2,
                             const int* __restrict__ gids,
                             const int* __restrict__ gcnt,
                             float* __restrict__ out, int n) {
    int gw = (blockIdx.x * blockDim.x + threadIdx.x) >> 6;
    int lane = threadIdx.x & 63;
    int wave = threadIdx.x >> 6;
    const ushort* hp = reinterpret_cast<const ushort*>(h);
    float val = 0.f;
    int g;
    if (gw < n) {
        g = gids[gw];
        int e0 = row_start[gw];
        int e1 = row_start[gw + 1];
        float acc = 0.f;
        int e = e0;
        for (; e + 16 <= e1; e += 16) {
            uint v[16];
#pragma unroll
            for (int j = 0; j < 16; ++j)
                v[j] = hp[(size_t)csr_src[e + j] * 64 + lane];
#pragma unroll
            for (int j = 0; j < 16; ++j) acc += __uint_as_float(v[j] << 16);
        }
        if (e + 8 <= e1) {
            uint v[8];
#pragma unroll
            for (int j = 0; j < 8; ++j)
                v[j] = hp[(size_t)csr_src[e + j] * 64 + lane];
#pragma unroll
            for (int j = 0; j < 8; ++j) acc += __uint_as_float(v[j] << 16);
            e += 8;
        }
        if (e + 4 <= e1) {
            uint v[4];
#pragma unroll
            for (int j = 0; j < 4; ++j)
                v[j] = hp[(size_t)csr_src[e + j] * 64 + lane];
#pragma unroll
            for (int j = 0; j < 4; ++j) acc += __uint_as_float(v[j] << 16);
            e += 4;
        }
        if (e + 2 <= e1) {
            uint v0 = hp[(size_t)csr_src[e] * 64 + lane];
            uint v1 = hp[(size_t)csr_src[e + 1] * 64 + lane];
            acc += __uint_as_float(v0 << 16);
            acc += __uint_as_float(v1 << 16);
            e += 2;
        }
        if (e < e1) {
            uint v0 = hp[(size_t)csr_src[e] * 64 + lane];
            acc += __uint_as_float(v0 << 16);
        }
        float nd = rsqrtf((float)max(e1 - e0, 1));
        val = fmaxf(fmaf(acc, nd, b2[lane]), 0.f);
        val *= 1.f / (float)max(gcnt[g], 1);
    } else {
        g = gids[n - 1];
    }
    __shared__ float sbuf[4][64];
    __shared__ int sg[4];
    sbuf[wave][lane] = val;
    if (lane == 0) sg[wave] = g;
    __syncthreads();
    if (wave == 0) {
        int g0 = sg[0], g1 = sg[1], g2 = sg[2], g3 = sg[3];
        if (g0 == g1 && g1 == g2 && g2 == g3) {
            float ssum = sbuf[0][lane] + sbuf[1][lane] + sbuf[2][lane] + sbuf[3][lane];
            atomicAdd(&out[(size_t)g0 * 64 + lane], ssum);
        } else {
            atomicAdd(&out[(size_t)g0 * 64 + lane], sbuf[0][lane]);
            atomicAdd(&out[(size_t)g1 * 64 + lane], sbuf[1][lane]);
            atomicAdd(&out[(size_t)g2 * 64 + lane], sbuf[2][lane]);
            atomicAdd(&out[(size_t)g3 * 64 + lane], sbuf[3][lane]);
        }
    }
}

extern "C" void kernel_launch(void* const* d_in, const int* in_sizes, int n_in,
                              void* d_out, int out_size, void* d_ws, size_t ws_size,
                              hipStream_t stream) {
    const float* features = (const float*)d_in[0];
    const float* W1 = (const float*)d_in[1];
    const float* b1 = (const float*)d_in[2];
    const float* W2 = (const float*)d_in[3];
    const float* b2 = (const float*)d_in[4];
    const int* src = (const int*)d_in[5];
    const int* dst = (const int*)d_in[6];
    const int* gids = (const int*)d_in[7];
    const int N = in_sizes[7];
    const int E = in_sizes[5];
    const int G = out_size / 64;  // out_size is FLOAT ELEMENTS: [G][64] f32
    float* out = (float*)d_out;
    const int P = (N + NPP - 1) >> NPP_SHIFT;

    char* ws = (char*)d_ws;
    size_t off = 0;
    auto alloc = [&](size_t bytes) -> void* {
        void* p = ws + off;
        off = (off + bytes + 255) & ~(size_t)255;
        return p;
    };
    int* counts = (int*)alloc((size_t)2 * NB * P * 4);
    int* offs = (int*)alloc((size_t)2 * NB * P * 4);
    int* ptot = (int*)alloc((size_t)2 * P * 4);
    int* pbase = (int*)alloc((size_t)2 * P * 4);
    int* gcnt = (int*)alloc((size_t)G * 4);
    int* ebuf_src = (int*)alloc((size_t)E * 4);
    int2* ebuf_dst = (int2*)alloc((size_t)E * 8);
    float* norm_src = (float*)alloc((size_t)N * 4);
    int* row_start = (int*)alloc((size_t)(N + 1) * 4);
    int* csr_src = (int*)alloc((size_t)E * 4);
    uint* h1 = (uint*)alloc((size_t)N * 128);                            // fp8 [N][128]
    __hip_bfloat16* x2n = (__hip_bfloat16*)alloc((size_t)N * 128 * 2);   // bf16, permuted
    __hip_bfloat16* h2 = (__hip_bfloat16*)h1;  // h1 dead after spmm1; 12.8MB each

    hipMemsetAsync(out, 0, (size_t)out_size * sizeof(float), stream);
    hipMemsetAsync(gcnt, 0, (size_t)G * 4, stream);

    const int B = 256;
    // --- atomic-free graph build + per-graph node counts ---
    passA_count<<<NB, 256, 0, stream>>>(src, dst, E, P, counts, counts + (size_t)NB * P,
                                        gids, N, G, gcnt);
    scanB<<<2 * P, 1024, 0, stream>>>(counts, offs, ptot, P);
    passC_scatter<<<NB, 256, 0, stream>>>(src, dst, E, P, offs, ptot, pbase,
                                          ebuf_src, ebuf_dst);
    passD_build<<<P, 512, 0, stream>>>(ebuf_src, ebuf_dst, ptot, pbase, norm_src, row_start,
                                       csr_src, N, E, P);

    // Layer 1: h1(fp8, permuted) = (features * norm_src) @ W1
    gemm_mfma<128, false, false, true><<<768, 256, 0, stream>>>(features, W1, norm_src,
                                                                (void*)h1, N);
    spmm1_kernel<<<(N * 64 + B - 1) / B, B, 0, stream>>>(h1, row_start, csr_src, b1, norm_src,
                                                         (uint2*)x2n, N);
    // Layer 2: h2(bf16, standard) = x2n(permuted) @ W2  (W rows permuted to match)
    gemm_mfma<64, true, true, false><<<768, 256, 0, stream>>>(x2n, W2, nullptr,
                                                              (void*)h2, N);
    // SpMM + fused mean-pool
    spmm2_kernel<<<(N * 64 + B - 1) / B, B, 0, stream>>>(h2, row_start, csr_src, b2,
                                                         gids, gcnt, out, N);
}

// Round 3
// 290.994 us; speedup vs baseline: 1.1395x; 1.0484x over previous
//
#include <hip/hip_runtime.h>
#include <hip/hip_bf16.h>

// ---------------------------------------------------------------------------
// GCN 2-layer forward on MI355X.
// Round 13: h2 stored fp8-e4m3 (64B rows, 6.4MB working set -> mostly
// L2-resident; 2 rows/line). spmm2 gathers 4 edges per load instruction
// (16 lanes x u32 per edge), quartering load-issue count. gemm2 epilogue
// packs fp8 (slot s byte c <-> feat 16c+s); spmm2 bias gather + pool write
// absorb the permutation. R12 (fp8 h1, fused pool) retained.
// ---------------------------------------------------------------------------

#define NPP_SHIFT 9
#define NPP 512
#define MAXP 256
#define NB 512

typedef __attribute__((ext_vector_type(8))) short frag8;
typedef __attribute__((ext_vector_type(4))) float f32x4;
typedef __attribute__((ext_vector_type(2))) float v2f;

// ---- Pass A: per-block histograms of src/dst partitions + graph counts --
__launch_bounds__(256)
__global__ void passA_count(const int* __restrict__ src, const int* __restrict__ dst,
                            int E, int P, int* __restrict__ counts_src,
                            int* __restrict__ counts_dst,
                            const int* __restrict__ gids, int N, int G,
                            int* __restrict__ gcnt) {
    __shared__ int h1[MAXP], h2[MAXP], h3[MAXP];
    int tid = threadIdx.x;
    for (int i = tid; i < MAXP; i += 256) { h1[i] = 0; h2[i] = 0; h3[i] = 0; }
    __syncthreads();
    int per_block = (E + NB - 1) / NB;
    int e0 = blockIdx.x * per_block;
    int e1 = min(e0 + per_block, E);
    for (int e = e0 + tid; e < e1; e += 256) {
        atomicAdd(&h1[src[e] >> NPP_SHIFT], 1);
        atomicAdd(&h2[dst[e] >> NPP_SHIFT], 1);
    }
    int npb = (N + NB - 1) / NB;
    int n0 = blockIdx.x * npb;
    int n1 = min(n0 + npb, N);
    for (int i = n0 + tid; i < n1; i += 256) atomicAdd(&h3[gids[i]], 1);
    __syncthreads();
    for (int i = tid; i < P; i += 256) {
        counts_src[(size_t)blockIdx.x * P + i] = h1[i];
        counts_dst[(size_t)blockIdx.x * P + i] = h2[i];
    }
    for (int i = tid; i < G; i += 256)
        if (h3[i]) atomicAdd(&gcnt[i], h3[i]);
}

// ---- Pass B: exclusive scan across blocks for each (stream, partition) --
__launch_bounds__(1024)
__global__ void scanB(const int* __restrict__ counts, int* __restrict__ offs,
                      int* __restrict__ ptot, int P) {
    __shared__ int s[1024];
    int tid = threadIdx.x;
    int p = blockIdx.x % P;
    int st = blockIdx.x / P;
    const int* c = counts + (size_t)st * NB * P;
    int v = (tid < NB) ? c[(size_t)tid * P + p] : 0;
    s[tid] = v;
    __syncthreads();
    for (int off = 1; off < 1024; off <<= 1) {
        int t = (tid >= off) ? s[tid - off] : 0;
        __syncthreads();
        s[tid] += t;
        __syncthreads();
    }
    if (tid < NB) offs[(size_t)st * NB * P + (size_t)tid * P + p] = s[tid] - v;
    if (tid == 1023) ptot[st * P + p] = s[1023];
}

// ---- Pass C: scatter into partition-bucketed buffers (LDS cursors) ------
__launch_bounds__(256)
__global__ void passC_scatter(const int* __restrict__ src, const int* __restrict__ dst,
                              int E, int P, const int* __restrict__ offs,
                              const int* __restrict__ ptot, int* __restrict__ pbase,
                              int* __restrict__ ebuf_src, int2* __restrict__ ebuf_dst) {
    __shared__ int cur1[MAXP], cur2[MAXP], sc[256];
    int tid = threadIdx.x;
    int v = (tid < P) ? ptot[tid] : 0;
    sc[tid] = v;
    __syncthreads();
    for (int off = 1; off < 256; off <<= 1) {
        int t = (tid >= off) ? sc[tid - off] : 0;
        __syncthreads();
        sc[tid] += t;
        __syncthreads();
    }
    int base0 = sc[tid] - v;
    if (tid < P) {
        cur1[tid] = base0 + offs[(size_t)blockIdx.x * P + tid];
        if (blockIdx.x == 0) pbase[tid] = base0;
    }
    __syncthreads();
    v = (tid < P) ? ptot[P + tid] : 0;
    sc[tid] = v;
    __syncthreads();
    for (int off = 1; off < 256; off <<= 1) {
        int t = (tid >= off) ? sc[tid - off] : 0;
        __syncthreads();
        sc[tid] += t;
        __syncthreads();
    }
    int base1 = sc[tid] - v;
    if (tid < P) {
        cur2[tid] = base1 + offs[(size_t)NB * P + (size_t)blockIdx.x * P + tid];
        if (blockIdx.x == 0) pbase[P + tid] = base1;
    }
    __syncthreads();
    int per_block = (E + NB - 1) / NB;
    int e0 = blockIdx.x * per_block;
    int e1 = min(e0 + per_block, E);
    for (int e = e0 + tid; e < e1; e += 256) {
        int s = src[e];
        int d = dst[e];
        int pos1 = atomicAdd(&cur1[s >> NPP_SHIFT], 1);
        ebuf_src[pos1] = s;
        int pos2 = atomicAdd(&cur2[d >> NPP_SHIFT], 1);
        ebuf_dst[pos2] = make_int2(d, s);
    }
}

// ---- Pass D: per-partition degree/norm/row_start/csr build --------------
__launch_bounds__(512)
__global__ void passD_build(const int* __restrict__ ebuf_src, const int2* __restrict__ ebuf_dst,
                            const int* __restrict__ ptot, const int* __restrict__ pbase,
                            float* __restrict__ norm_src, int* __restrict__ row_start,
                            int* __restrict__ csr_src, int N, int E, int P) {
    __shared__ int hs[NPP], hd[NPP], sc[NPP];
    int tid = threadIdx.x;
    int p = blockIdx.x;
    int node_lo = p << NPP_SHIFT;
    int nl = min(NPP, N - node_lo);
    hs[tid] = 0;
    hd[tid] = 0;
    __syncthreads();
    int nsrc = ptot[p];
    int base_s = pbase[p];
    for (int i = tid; i < nsrc; i += 512)
        atomicAdd(&hs[ebuf_src[base_s + i] - node_lo], 1);
    int ndst = ptot[P + p];
    int base_d = pbase[P + p];
    for (int i = tid; i < ndst; i += 512)
        atomicAdd(&hd[ebuf_dst[base_d + i].x - node_lo], 1);
    __syncthreads();
    if (tid < nl) norm_src[node_lo + tid] = rsqrtf((float)max(hs[tid], 1));
    int myh = hd[tid];
    sc[tid] = myh;
    __syncthreads();
    for (int off = 1; off < 512; off <<= 1) {
        int t = (tid >= off) ? sc[tid - off] : 0;
        __syncthreads();
        sc[tid] += t;
        __syncthreads();
    }
    int row0 = base_d + sc[tid] - myh;
    if (tid < nl) row_start[node_lo + tid] = row0;
    if (p == P - 1 && tid == 0) row_start[N] = E;
    __syncthreads();
    hd[tid] = row0;  // reuse as cursor
    __syncthreads();
    for (int i = tid; i < ndst; i += 512) {
        int2 r = ebuf_dst[base_d + i];
        int pos = atomicAdd(&hd[r.x - node_lo], 1);
        csr_src[pos] = r.y;
    }
}

// ---- MFMA GEMM: out[n x COLS] = A[n x 128] @ W[128 x COLS] --------------
// FP8OUT, COLS==128: u32 slot s, byte c <-> feature 64*(s&1) + 16*c + (s>>1)
// FP8OUT, COLS==64:  u32 slot s, byte c <-> feature 16*c + s
// PERM: LDS W row k sources w[feat(k)] to absorb the permuted A layout.
template <int COLS, bool BF16IN, bool PERM, bool FP8OUT>
__launch_bounds__(256)
__global__ void gemm_mfma(const void* __restrict__ xin, const float* __restrict__ w,
                          const float* __restrict__ norm,
                          void* __restrict__ out, int n) {
    constexpr int NT = COLS / 16;
    __shared__ short wlds[4 * NT * 64 * 8];
    const int tid = threadIdx.x;
    for (int i = tid; i < 128 * COLS / 4; i += 256) {
        int k = (i * 4) / COLS;
        int n0 = (i * 4) % COLS;
        float4 wv;
        if constexpr (PERM) {
            int ksrc = 64 * ((k >> 2) & 1) + 16 * (k & 3) + (k >> 3);
            wv = *reinterpret_cast<const float4*>(w + (size_t)ksrc * COLS + n0);
        } else {
            wv = reinterpret_cast<const float4*>(w)[i];
        }
        int c = k >> 5, q = (k >> 3) & 3, j = k & 7;
        float vals[4] = {wv.x, wv.y, wv.z, wv.w};
#pragma unroll
        for (int u = 0; u < 4; ++u) {
            int nn = n0 + u;
            int t = nn >> 4;
            int ln = (q << 4) | (nn & 15);
            union { __hip_bfloat16 b; short s; } cv;
            cv.b = __float2bfloat16(vals[u]);
            wlds[(((c * NT + t) << 6) | ln) * 8 + j] = cv.s;
        }
    }
    __syncthreads();

    const int lane = tid & 63;
    const int wid = tid >> 6;
    const int m = lane & 15;
    const int q = lane >> 4;
    const int ntiles = (n + 15) >> 4;
    const frag8* wfr = reinterpret_cast<const frag8*>(wlds);

    for (int wt = blockIdx.x * 4 + wid; wt < ntiles; wt += gridDim.x * 4) {
        const int row = (wt << 4) + m;
        frag8 af[4];
        if (row < n) {
            if constexpr (BF16IN) {
                const frag8* xp = reinterpret_cast<const frag8*>(
                    (const __hip_bfloat16*)xin + (size_t)row * 128);
#pragma unroll
                for (int c = 0; c < 4; ++c) af[c] = xp[c * 4 + q];
            } else {
                const float* xp = (const float*)xin + (size_t)row * 128;
                float nm = norm[row];
#pragma unroll
                for (int c = 0; c < 4; ++c) {
                    int base = c * 32 + q * 8;
                    float4 v0 = *reinterpret_cast<const float4*>(xp + base);
                    float4 v1 = *reinterpret_cast<const float4*>(xp + base + 4);
                    union { frag8 f; short s[8]; } a;
                    union { __hip_bfloat16 b; short s; } cv;
                    cv.b = __float2bfloat16(v0.x * nm); a.s[0] = cv.s;
                    cv.b = __float2bfloat16(v0.y * nm); a.s[1] = cv.s;
                    cv.b = __float2bfloat16(v0.z * nm); a.s[2] = cv.s;
                    cv.b = __float2bfloat16(v0.w * nm); a.s[3] = cv.s;
                    cv.b = __float2bfloat16(v1.x * nm); a.s[4] = cv.s;
                    cv.b = __float2bfloat16(v1.y * nm); a.s[5] = cv.s;
                    cv.b = __float2bfloat16(v1.z * nm); a.s[6] = cv.s;
                    cv.b = __float2bfloat16(v1.w * nm); a.s[7] = cv.s;
                    af[c] = a.f;
                }
            }
        } else {
#pragma unroll
            for (int c = 0; c < 4; ++c) af[c] = frag8{0, 0, 0, 0, 0, 0, 0, 0};
        }
        f32x4 acc[NT] = {};
#pragma unroll
        for (int c = 0; c < 4; ++c)
#pragma unroll
            for (int t = 0; t < NT; ++t)
                acc[t] = __builtin_amdgcn_mfma_f32_16x16x32_bf16(
                    af[c], wfr[(c * NT + t) * 64 + lane], acc[t], 0, 0, 0);
#pragma unroll
        for (int r = 0; r < 4; ++r) {
            int grow = (wt << 4) + q * 4 + r;
            if (grow < n) {
                if constexpr (FP8OUT && COLS == 128) {
                    // pack 8 feats {16t+m} into 2 u32: slot 2m (t=0..3), 2m+1 (t=4..7)
                    uint w0 = 0, w1 = 0;
                    w0 = (uint)__builtin_amdgcn_cvt_pk_fp8_f32(acc[0][r], acc[1][r], (int)w0, false);
                    w0 = (uint)__builtin_amdgcn_cvt_pk_fp8_f32(acc[2][r], acc[3][r], (int)w0, true);
                    w1 = (uint)__builtin_amdgcn_cvt_pk_fp8_f32(acc[4][r], acc[5][r], (int)w1, false);
                    w1 = (uint)__builtin_amdgcn_cvt_pk_fp8_f32(acc[6][r], acc[7][r], (int)w1, true);
                    reinterpret_cast<uint2*>(out)[(size_t)grow * 16 + m] = make_uint2(w0, w1);
                } else if constexpr (FP8OUT) {
                    // COLS==64: pack feats {16c+m} into 1 u32 at slot m
                    uint w0 = 0;
                    w0 = (uint)__builtin_amdgcn_cvt_pk_fp8_f32(acc[0][r], acc[1][r], (int)w0, false);
                    w0 = (uint)__builtin_amdgcn_cvt_pk_fp8_f32(acc[2][r], acc[3][r], (int)w0, true);
                    reinterpret_cast<uint*>(out)[(size_t)grow * 16 + m] = w0;
                } else {
                    __hip_bfloat16* ob = reinterpret_cast<__hip_bfloat16*>(out);
#pragma unroll
                    for (int t = 0; t < NT; ++t)
                        ob[(size_t)grow * COLS + t * 16 + m] = __float2bfloat16(acc[t][r]);
                }
            }
        }
    }
}

// ---- SpMM layer 1: wave per dst node, 2 edges/wave, fp8 gathers ---------
// h1 row = 32 u32 (128B, one line). lane: a=lane>>5 edge parity, s=lane&31 slot.
__launch_bounds__(256)
__global__ void spmm1_kernel(const uint* __restrict__ h1,
                             const int* __restrict__ row_start,
                             const int* __restrict__ csr_src,
                             const float* __restrict__ b1,
                             const float* __restrict__ norm_src,
                             uint2* __restrict__ x2n, int n) {
    int gw = (blockIdx.x * blockDim.x + threadIdx.x) >> 6;
    int lane = threadIdx.x & 63;
    if (gw >= n) return;
    int e0 = row_start[gw];
    int e1 = row_start[gw + 1];
    int a = lane >> 5;
    int s = lane & 31;
    float acc0 = 0.f, acc1 = 0.f, acc2 = 0.f, acc3 = 0.f;
    int e = e0;
    for (; e + 16 <= e1; e += 16) {
        uint v[8];
#pragma unroll
        for (int j = 0; j < 8; ++j) {
            int cs = csr_src[e + 2 * j + a];
            v[j] = h1[(size_t)cs * 32 + s];
        }
#pragma unroll
        for (int j = 0; j < 8; ++j) {
            v2f lo = __builtin_amdgcn_cvt_pk_f32_fp8((int)v[j], false);
            v2f hi = __builtin_amdgcn_cvt_pk_f32_fp8((int)v[j], true);
            acc0 += lo[0]; acc1 += lo[1]; acc2 += hi[0]; acc3 += hi[1];
        }
    }
    if (e < e1) {  // masked tail batch (covers up to 15 edges); fp8 0x00 == 0.0f
        uint v[8];
#pragma unroll
        for (int j = 0; j < 8; ++j) {
            int idx = e + 2 * j + a;
            int cidx = min(idx, e1 - 1);
            int cs = csr_src[cidx];
            uint vv = h1[(size_t)cs * 32 + s];
            v[j] = (idx < e1) ? vv : 0u;
        }
#pragma unroll
        for (int j = 0; j < 8; ++j) {
            v2f lo = __builtin_amdgcn_cvt_pk_f32_fp8((int)v[j], false);
            v2f hi = __builtin_amdgcn_cvt_pk_f32_fp8((int)v[j], true);
            acc0 += lo[0]; acc1 += lo[1]; acc2 += hi[0]; acc3 += hi[1];
        }
    }
    acc0 += __shfl_xor(acc0, 32);
    acc1 += __shfl_xor(acc1, 32);
    acc2 += __shfl_xor(acc2, 32);
    acc3 += __shfl_xor(acc3, 32);
    if (a == 0) {
        float nd = rsqrtf((float)max(e1 - e0, 1));
        float ns = norm_src[gw];
        int m2 = s >> 1;
        int a2 = (s & 1) << 6;
        float f0 = fmaxf(fmaf(acc0, nd, b1[a2 + m2]), 0.f) * ns;
        float f1 = fmaxf(fmaf(acc1, nd, b1[a2 + 16 + m2]), 0.f) * ns;
        float f2 = fmaxf(fmaf(acc2, nd, b1[a2 + 32 + m2]), 0.f) * ns;
        float f3 = fmaxf(fmaf(acc3, nd, b1[a2 + 48 + m2]), 0.f) * ns;
        union { __hip_bfloat16 b; ushort u; } c0, c1, c2, c3;
        c0.b = __float2bfloat16(f0);
        c1.b = __float2bfloat16(f1);
        c2.b = __float2bfloat16(f2);
        c3.b = __float2bfloat16(f3);
        uint w0 = (uint)c0.u | ((uint)c1.u << 16);
        uint w1 = (uint)c2.u | ((uint)c3.u << 16);
        x2n[(size_t)gw * 32 + s] = make_uint2(w0, w1);
    }
}

// ---- SpMM layer 2 + fused mean-pool: fp8 gathers (4 edges/instr) --------
// h2 row = 16 u32 (64B). lane: a=lane>>4 edge sub-idx, s=lane&15 slot.
// slot s byte c <-> feat 16c+s.
__launch_bounds__(256)
__global__ void spmm2_kernel(const uint* __restrict__ h2,
                             const int* __restrict__ row_start,
                             const int* __restrict__ csr_src,
                             const float* __restrict__ b2,
                             const int* __restrict__ gids,
                             const int* __restrict__ gcnt,
                             float* __restrict__ out, int n) {
    int gw = (blockIdx.x * blockDim.x + threadIdx.x) >> 6;
    int lane = threadIdx.x & 63;
    int wave = threadIdx.x >> 6;
    int a = lane >> 4;
    int s = lane & 15;
    float f0 = 0.f, f1 = 0.f, f2 = 0.f, f3 = 0.f;
    int g;
    if (gw < n) {
        g = gids[gw];
        int e0 = row_start[gw];
        int e1 = row_start[gw + 1];
        float v0 = 0.f, v1 = 0.f, v2 = 0.f, v3 = 0.f;
        int e = e0;
        for (; e + 16 <= e1; e += 16) {
            uint u[4];
#pragma unroll
            for (int j = 0; j < 4; ++j)
                u[j] = h2[(size_t)csr_src[e + 4 * j + a] * 16 + s];
#pragma unroll
            for (int j = 0; j < 4; ++j) {
                v2f lo = __builtin_amdgcn_cvt_pk_f32_fp8((int)u[j], false);
                v2f hi = __builtin_amdgcn_cvt_pk_f32_fp8((int)u[j], true);
                v0 += lo[0]; v1 += lo[1]; v2 += hi[0]; v3 += hi[1];
            }
        }
        if (e < e1) {  // masked tail (up to 15 edges)
            uint u[4];
#pragma unroll
            for (int j = 0; j < 4; ++j) {
                int idx = e + 4 * j + a;
                int cidx = min(idx, e1 - 1);
                uint vv = h2[(size_t)csr_src[cidx] * 16 + s];
                u[j] = (idx < e1) ? vv : 0u;
            }
#pragma unroll
            for (int j = 0; j < 4; ++j) {
                v2f lo = __builtin_amdgcn_cvt_pk_f32_fp8((int)u[j], false);
                v2f hi = __builtin_amdgcn_cvt_pk_f32_fp8((int)u[j], true);
                v0 += lo[0]; v1 += lo[1]; v2 += hi[0]; v3 += hi[1];
            }
        }
        v0 += __shfl_xor(v0, 16); v0 += __shfl_xor(v0, 32);
        v1 += __shfl_xor(v1, 16); v1 += __shfl_xor(v1, 32);
        v2 += __shfl_xor(v2, 16); v2 += __shfl_xor(v2, 32);
        v3 += __shfl_xor(v3, 16); v3 += __shfl_xor(v3, 32);
        float nd = rsqrtf((float)max(e1 - e0, 1));
        float inv = 1.f / (float)max(gcnt[g], 1);
        f0 = fmaxf(fmaf(v0, nd, b2[s]), 0.f) * inv;
        f1 = fmaxf(fmaf(v1, nd, b2[16 + s]), 0.f) * inv;
        f2 = fmaxf(fmaf(v2, nd, b2[32 + s]), 0.f) * inv;
        f3 = fmaxf(fmaf(v3, nd, b2[48 + s]), 0.f) * inv;
    } else {
        g = gids[n - 1];
    }
    __shared__ float sbuf[4][64];
    __shared__ int sg[4];
    if (a == 0) {
        sbuf[wave][s] = f0;
        sbuf[wave][16 + s] = f1;
        sbuf[wave][32 + s] = f2;
        sbuf[wave][48 + s] = f3;
    }
    if (lane == 0) sg[wave] = g;
    __syncthreads();
    if (wave == 0) {
        int g0 = sg[0], g1 = sg[1], g2 = sg[2], g3 = sg[3];
        if (g0 == g1 && g1 == g2 && g2 == g3) {
            float ssum = sbuf[0][lane] + sbuf[1][lane] + sbuf[2][lane] + sbuf[3][lane];
            atomicAdd(&out[(size_t)g0 * 64 + lane], ssum);
        } else {
            atomicAdd(&out[(size_t)g0 * 64 + lane], sbuf[0][lane]);
            atomicAdd(&out[(size_t)g1 * 64 + lane], sbuf[1][lane]);
            atomicAdd(&out[(size_t)g2 * 64 + lane], sbuf[2][lane]);
            atomicAdd(&out[(size_t)g3 * 64 + lane], sbuf[3][lane]);
        }
    }
}

extern "C" void kernel_launch(void* const* d_in, const int* in_sizes, int n_in,
                              void* d_out, int out_size, void* d_ws, size_t ws_size,
                              hipStream_t stream) {
    const float* features = (const float*)d_in[0];
    const float* W1 = (const float*)d_in[1];
    const float* b1 = (const float*)d_in[2];
    const float* W2 = (const float*)d_in[3];
    const float* b2 = (const float*)d_in[4];
    const int* src = (const int*)d_in[5];
    const int* dst = (const int*)d_in[6];
    const int* gids = (const int*)d_in[7];
    const int N = in_sizes[7];
    const int E = in_sizes[5];
    const int G = out_size / 64;  // out_size is FLOAT ELEMENTS: [G][64] f32
    float* out = (float*)d_out;
    const int P = (N + NPP - 1) >> NPP_SHIFT;

    char* ws = (char*)d_ws;
    size_t off = 0;
    auto alloc = [&](size_t bytes) -> void* {
        void* p = ws + off;
        off = (off + bytes + 255) & ~(size_t)255;
        return p;
    };
    int* counts = (int*)alloc((size_t)2 * NB * P * 4);
    int* offs = (int*)alloc((size_t)2 * NB * P * 4);
    int* ptot = (int*)alloc((size_t)2 * P * 4);
    int* pbase = (int*)alloc((size_t)2 * P * 4);
    int* gcnt = (int*)alloc((size_t)G * 4);
    int* ebuf_src = (int*)alloc((size_t)E * 4);
    int2* ebuf_dst = (int2*)alloc((size_t)E * 8);
    float* norm_src = (float*)alloc((size_t)N * 4);
    int* row_start = (int*)alloc((size_t)(N + 1) * 4);
    int* csr_src = (int*)alloc((size_t)E * 4);
    uint* h1 = (uint*)alloc((size_t)N * 128);                            // fp8 [N][128]
    __hip_bfloat16* x2n = (__hip_bfloat16*)alloc((size_t)N * 128 * 2);   // bf16, permuted
    uint* h2 = h1;  // fp8 [N][64] (64B rows); h1 dead after spmm1

    hipMemsetAsync(out, 0, (size_t)out_size * sizeof(float), stream);
    hipMemsetAsync(gcnt, 0, (size_t)G * 4, stream);

    const int B = 256;
    // --- atomic-free graph build + per-graph node counts ---
    passA_count<<<NB, 256, 0, stream>>>(src, dst, E, P, counts, counts + (size_t)NB * P,
                                        gids, N, G, gcnt);
    scanB<<<2 * P, 1024, 0, stream>>>(counts, offs, ptot, P);
    passC_scatter<<<NB, 256, 0, stream>>>(src, dst, E, P, offs, ptot, pbase,
                                          ebuf_src, ebuf_dst);
    passD_build<<<P, 512, 0, stream>>>(ebuf_src, ebuf_dst, ptot, pbase, norm_src, row_start,
                                       csr_src, N, E, P);

    // Layer 1: h1(fp8, permuted) = (features * norm_src) @ W1
    gemm_mfma<128, false, false, true><<<768, 256, 0, stream>>>(features, W1, norm_src,
                                                                (void*)h1, N);
    spmm1_kernel<<<(N * 64 + B - 1) / B, B, 0, stream>>>(h1, row_start, csr_src, b1, norm_src,
                                                         (uint2*)x2n, N);
    // Layer 2: h2(fp8, 64B rows) = x2n(permuted) @ W2  (W rows permuted to match)
    gemm_mfma<64, true, true, true><<<768, 256, 0, stream>>>(x2n, W2, nullptr,
                                                             (void*)h2, N);
    // SpMM + fused mean-pool (4 edges per load instruction)
    spmm2_kernel<<<(N * 64 + B - 1) / B, B, 0, stream>>>(h2, row_start, csr_src, b2,
                                                         gids, gcnt, out, N);
}

// Round 4
// 287.913 us; speedup vs baseline: 1.1517x; 1.0107x over previous
//
#include <hip/hip_runtime.h>
#include <hip/hip_bf16.h>

// ---------------------------------------------------------------------------
// GCN 2-layer forward on MI355X.
// Round 14: latency attack on both SpMMs (R13: spmm2 at 50us with HBM 15%,
// VALU 44% -> latency-bound, 1 row/wave = 4 loads in flight, serial chain
// row_start->csr->gather). spmm2 now 4 rows/wave (16 gathers in flight),
// spmm1 2 rows/wave (16 gathers in flight); uniform masked batches
// (wave-uniform conditions). Pool fusion: in-register 4-row sum when same
// graph (gids sorted -> ~99.9%), slow-path atomics otherwise.
// R12/R13 retained: fp8 h1 (128B rows) + fp8 h2 (64B rows), fused pool,
// fp8 gemm epilogues with absorbed permutations.
// ---------------------------------------------------------------------------

#define NPP_SHIFT 9
#define NPP 512
#define MAXP 256
#define NB 512

typedef __attribute__((ext_vector_type(8))) short frag8;
typedef __attribute__((ext_vector_type(4))) float f32x4;
typedef __attribute__((ext_vector_type(2))) float v2f;

// ---- Pass A: per-block histograms of src/dst partitions + graph counts --
__launch_bounds__(256)
__global__ void passA_count(const int* __restrict__ src, const int* __restrict__ dst,
                            int E, int P, int* __restrict__ counts_src,
                            int* __restrict__ counts_dst,
                            const int* __restrict__ gids, int N, int G,
                            int* __restrict__ gcnt) {
    __shared__ int h1[MAXP], h2[MAXP], h3[MAXP];
    int tid = threadIdx.x;
    for (int i = tid; i < MAXP; i += 256) { h1[i] = 0; h2[i] = 0; h3[i] = 0; }
    __syncthreads();
    int per_block = (E + NB - 1) / NB;
    int e0 = blockIdx.x * per_block;
    int e1 = min(e0 + per_block, E);
    for (int e = e0 + tid; e < e1; e += 256) {
        atomicAdd(&h1[src[e] >> NPP_SHIFT], 1);
        atomicAdd(&h2[dst[e] >> NPP_SHIFT], 1);
    }
    int npb = (N + NB - 1) / NB;
    int n0 = blockIdx.x * npb;
    int n1 = min(n0 + npb, N);
    for (int i = n0 + tid; i < n1; i += 256) atomicAdd(&h3[gids[i]], 1);
    __syncthreads();
    for (int i = tid; i < P; i += 256) {
        counts_src[(size_t)blockIdx.x * P + i] = h1[i];
        counts_dst[(size_t)blockIdx.x * P + i] = h2[i];
    }
    for (int i = tid; i < G; i += 256)
        if (h3[i]) atomicAdd(&gcnt[i], h3[i]);
}

// ---- Pass B: exclusive scan across blocks for each (stream, partition) --
__launch_bounds__(1024)
__global__ void scanB(const int* __restrict__ counts, int* __restrict__ offs,
                      int* __restrict__ ptot, int P) {
    __shared__ int s[1024];
    int tid = threadIdx.x;
    int p = blockIdx.x % P;
    int st = blockIdx.x / P;
    const int* c = counts + (size_t)st * NB * P;
    int v = (tid < NB) ? c[(size_t)tid * P + p] : 0;
    s[tid] = v;
    __syncthreads();
    for (int off = 1; off < 1024; off <<= 1) {
        int t = (tid >= off) ? s[tid - off] : 0;
        __syncthreads();
        s[tid] += t;
        __syncthreads();
    }
    if (tid < NB) offs[(size_t)st * NB * P + (size_t)tid * P + p] = s[tid] - v;
    if (tid == 1023) ptot[st * P + p] = s[1023];
}

// ---- Pass C: scatter into partition-bucketed buffers (LDS cursors) ------
__launch_bounds__(256)
__global__ void passC_scatter(const int* __restrict__ src, const int* __restrict__ dst,
                              int E, int P, const int* __restrict__ offs,
                              const int* __restrict__ ptot, int* __restrict__ pbase,
                              int* __restrict__ ebuf_src, int2* __restrict__ ebuf_dst) {
    __shared__ int cur1[MAXP], cur2[MAXP], sc[256];
    int tid = threadIdx.x;
    int v = (tid < P) ? ptot[tid] : 0;
    sc[tid] = v;
    __syncthreads();
    for (int off = 1; off < 256; off <<= 1) {
        int t = (tid >= off) ? sc[tid - off] : 0;
        __syncthreads();
        sc[tid] += t;
        __syncthreads();
    }
    int base0 = sc[tid] - v;
    if (tid < P) {
        cur1[tid] = base0 + offs[(size_t)blockIdx.x * P + tid];
        if (blockIdx.x == 0) pbase[tid] = base0;
    }
    __syncthreads();
    v = (tid < P) ? ptot[P + tid] : 0;
    sc[tid] = v;
    __syncthreads();
    for (int off = 1; off < 256; off <<= 1) {
        int t = (tid >= off) ? sc[tid - off] : 0;
        __syncthreads();
        sc[tid] += t;
        __syncthreads();
    }
    int base1 = sc[tid] - v;
    if (tid < P) {
        cur2[tid] = base1 + offs[(size_t)NB * P + (size_t)blockIdx.x * P + tid];
        if (blockIdx.x == 0) pbase[P + tid] = base1;
    }
    __syncthreads();
    int per_block = (E + NB - 1) / NB;
    int e0 = blockIdx.x * per_block;
    int e1 = min(e0 + per_block, E);
    for (int e = e0 + tid; e < e1; e += 256) {
        int s = src[e];
        int d = dst[e];
        int pos1 = atomicAdd(&cur1[s >> NPP_SHIFT], 1);
        ebuf_src[pos1] = s;
        int pos2 = atomicAdd(&cur2[d >> NPP_SHIFT], 1);
        ebuf_dst[pos2] = make_int2(d, s);
    }
}

// ---- Pass D: per-partition degree/norm/row_start/csr build --------------
__launch_bounds__(512)
__global__ void passD_build(const int* __restrict__ ebuf_src, const int2* __restrict__ ebuf_dst,
                            const int* __restrict__ ptot, const int* __restrict__ pbase,
                            float* __restrict__ norm_src, int* __restrict__ row_start,
                            int* __restrict__ csr_src, int N, int E, int P) {
    __shared__ int hs[NPP], hd[NPP], sc[NPP];
    int tid = threadIdx.x;
    int p = blockIdx.x;
    int node_lo = p << NPP_SHIFT;
    int nl = min(NPP, N - node_lo);
    hs[tid] = 0;
    hd[tid] = 0;
    __syncthreads();
    int nsrc = ptot[p];
    int base_s = pbase[p];
    for (int i = tid; i < nsrc; i += 512)
        atomicAdd(&hs[ebuf_src[base_s + i] - node_lo], 1);
    int ndst = ptot[P + p];
    int base_d = pbase[P + p];
    for (int i = tid; i < ndst; i += 512)
        atomicAdd(&hd[ebuf_dst[base_d + i].x - node_lo], 1);
    __syncthreads();
    if (tid < nl) norm_src[node_lo + tid] = rsqrtf((float)max(hs[tid], 1));
    int myh = hd[tid];
    sc[tid] = myh;
    __syncthreads();
    for (int off = 1; off < 512; off <<= 1) {
        int t = (tid >= off) ? sc[tid - off] : 0;
        __syncthreads();
        sc[tid] += t;
        __syncthreads();
    }
    int row0 = base_d + sc[tid] - myh;
    if (tid < nl) row_start[node_lo + tid] = row0;
    if (p == P - 1 && tid == 0) row_start[N] = E;
    __syncthreads();
    hd[tid] = row0;  // reuse as cursor
    __syncthreads();
    for (int i = tid; i < ndst; i += 512) {
        int2 r = ebuf_dst[base_d + i];
        int pos = atomicAdd(&hd[r.x - node_lo], 1);
        csr_src[pos] = r.y;
    }
}

// ---- MFMA GEMM: out[n x COLS] = A[n x 128] @ W[128 x COLS] --------------
// FP8OUT, COLS==128: u32 slot s, byte c <-> feature 64*(s&1) + 16*c + (s>>1)
// FP8OUT, COLS==64:  u32 slot s, byte c <-> feature 16*c + s
// PERM: LDS W row k sources w[feat(k)] to absorb the permuted A layout.
template <int COLS, bool BF16IN, bool PERM, bool FP8OUT>
__launch_bounds__(256)
__global__ void gemm_mfma(const void* __restrict__ xin, const float* __restrict__ w,
                          const float* __restrict__ norm,
                          void* __restrict__ out, int n) {
    constexpr int NT = COLS / 16;
    __shared__ short wlds[4 * NT * 64 * 8];
    const int tid = threadIdx.x;
    for (int i = tid; i < 128 * COLS / 4; i += 256) {
        int k = (i * 4) / COLS;
        int n0 = (i * 4) % COLS;
        float4 wv;
        if constexpr (PERM) {
            int ksrc = 64 * ((k >> 2) & 1) + 16 * (k & 3) + (k >> 3);
            wv = *reinterpret_cast<const float4*>(w + (size_t)ksrc * COLS + n0);
        } else {
            wv = reinterpret_cast<const float4*>(w)[i];
        }
        int c = k >> 5, q = (k >> 3) & 3, j = k & 7;
        float vals[4] = {wv.x, wv.y, wv.z, wv.w};
#pragma unroll
        for (int u = 0; u < 4; ++u) {
            int nn = n0 + u;
            int t = nn >> 4;
            int ln = (q << 4) | (nn & 15);
            union { __hip_bfloat16 b; short s; } cv;
            cv.b = __float2bfloat16(vals[u]);
            wlds[(((c * NT + t) << 6) | ln) * 8 + j] = cv.s;
        }
    }
    __syncthreads();

    const int lane = tid & 63;
    const int wid = tid >> 6;
    const int m = lane & 15;
    const int q = lane >> 4;
    const int ntiles = (n + 15) >> 4;
    const frag8* wfr = reinterpret_cast<const frag8*>(wlds);

    for (int wt = blockIdx.x * 4 + wid; wt < ntiles; wt += gridDim.x * 4) {
        const int row = (wt << 4) + m;
        frag8 af[4];
        if (row < n) {
            if constexpr (BF16IN) {
                const frag8* xp = reinterpret_cast<const frag8*>(
                    (const __hip_bfloat16*)xin + (size_t)row * 128);
#pragma unroll
                for (int c = 0; c < 4; ++c) af[c] = xp[c * 4 + q];
            } else {
                const float* xp = (const float*)xin + (size_t)row * 128;
                float nm = norm[row];
#pragma unroll
                for (int c = 0; c < 4; ++c) {
                    int base = c * 32 + q * 8;
                    float4 v0 = *reinterpret_cast<const float4*>(xp + base);
                    float4 v1 = *reinterpret_cast<const float4*>(xp + base + 4);
                    union { frag8 f; short s[8]; } a;
                    union { __hip_bfloat16 b; short s; } cv;
                    cv.b = __float2bfloat16(v0.x * nm); a.s[0] = cv.s;
                    cv.b = __float2bfloat16(v0.y * nm); a.s[1] = cv.s;
                    cv.b = __float2bfloat16(v0.z * nm); a.s[2] = cv.s;
                    cv.b = __float2bfloat16(v0.w * nm); a.s[3] = cv.s;
                    cv.b = __float2bfloat16(v1.x * nm); a.s[4] = cv.s;
                    cv.b = __float2bfloat16(v1.y * nm); a.s[5] = cv.s;
                    cv.b = __float2bfloat16(v1.z * nm); a.s[6] = cv.s;
                    cv.b = __float2bfloat16(v1.w * nm); a.s[7] = cv.s;
                    af[c] = a.f;
                }
            }
        } else {
#pragma unroll
            for (int c = 0; c < 4; ++c) af[c] = frag8{0, 0, 0, 0, 0, 0, 0, 0};
        }
        f32x4 acc[NT] = {};
#pragma unroll
        for (int c = 0; c < 4; ++c)
#pragma unroll
            for (int t = 0; t < NT; ++t)
                acc[t] = __builtin_amdgcn_mfma_f32_16x16x32_bf16(
                    af[c], wfr[(c * NT + t) * 64 + lane], acc[t], 0, 0, 0);
#pragma unroll
        for (int r = 0; r < 4; ++r) {
            int grow = (wt << 4) + q * 4 + r;
            if (grow < n) {
                if constexpr (FP8OUT && COLS == 128) {
                    // pack 8 feats {16t+m} into 2 u32: slot 2m (t=0..3), 2m+1 (t=4..7)
                    uint w0 = 0, w1 = 0;
                    w0 = (uint)__builtin_amdgcn_cvt_pk_fp8_f32(acc[0][r], acc[1][r], (int)w0, false);
                    w0 = (uint)__builtin_amdgcn_cvt_pk_fp8_f32(acc[2][r], acc[3][r], (int)w0, true);
                    w1 = (uint)__builtin_amdgcn_cvt_pk_fp8_f32(acc[4][r], acc[5][r], (int)w1, false);
                    w1 = (uint)__builtin_amdgcn_cvt_pk_fp8_f32(acc[6][r], acc[7][r], (int)w1, true);
                    reinterpret_cast<uint2*>(out)[(size_t)grow * 16 + m] = make_uint2(w0, w1);
                } else if constexpr (FP8OUT) {
                    // COLS==64: pack feats {16c+m} into 1 u32 at slot m
                    uint w0 = 0;
                    w0 = (uint)__builtin_amdgcn_cvt_pk_fp8_f32(acc[0][r], acc[1][r], (int)w0, false);
                    w0 = (uint)__builtin_amdgcn_cvt_pk_fp8_f32(acc[2][r], acc[3][r], (int)w0, true);
                    reinterpret_cast<uint*>(out)[(size_t)grow * 16 + m] = w0;
                } else {
                    __hip_bfloat16* ob = reinterpret_cast<__hip_bfloat16*>(out);
#pragma unroll
                    for (int t = 0; t < NT; ++t)
                        ob[(size_t)grow * COLS + t * 16 + m] = __float2bfloat16(acc[t][r]);
                }
            }
        }
    }
}

// ---- SpMM layer 1: 2 dst rows per wave, fp8 gathers (2 edges/instr) -----
// h1 row = 32 u32 (128B). lane: a=lane>>5 edge parity, s=lane&31 slot.
// 16 gather loads in flight per wave (2 rows x 8).
__launch_bounds__(256)
__global__ void spmm1_kernel(const uint* __restrict__ h1,
                             const int* __restrict__ row_start,
                             const int* __restrict__ csr_src,
                             const float* __restrict__ b1,
                             const float* __restrict__ norm_src,
                             uint2* __restrict__ x2n, int n) {
    int wv = (blockIdx.x * blockDim.x + threadIdx.x) >> 6;
    int lane = threadIdx.x & 63;
    int r0 = wv * 2;
    if (r0 >= n) return;
    int a = lane >> 5;
    int s = lane & 31;
    int e0[2], e1[2];
#pragma unroll
    for (int r = 0; r < 2; ++r) {
        int rr = min(r0 + r, n - 1);
        e0[r] = row_start[rr];
        e1[r] = row_start[rr + 1];
        if (r0 + r >= n) e1[r] = e0[r];
    }
    float acc[2][4] = {};
    int nb = max((e1[0] - e0[0] + 15) >> 4, (e1[1] - e0[1] + 15) >> 4);
    for (int b = 0; b < nb; ++b) {
        uint v[2][8];
#pragma unroll
        for (int r = 0; r < 2; ++r) {
            int base = e0[r] + b * 16;
            if (base < e1[r]) {  // wave-uniform
#pragma unroll
                for (int j = 0; j < 8; ++j) {
                    int idx = base + 2 * j + a;
                    int cidx = min(idx, e1[r] - 1);
                    uint vv = h1[(size_t)csr_src[cidx] * 32 + s];
                    v[r][j] = (idx < e1[r]) ? vv : 0u;
                }
            } else {
#pragma unroll
                for (int j = 0; j < 8; ++j) v[r][j] = 0u;
            }
        }
#pragma unroll
        for (int r = 0; r < 2; ++r)
#pragma unroll
            for (int j = 0; j < 8; ++j) {
                v2f lo = __builtin_amdgcn_cvt_pk_f32_fp8((int)v[r][j], false);
                v2f hi = __builtin_amdgcn_cvt_pk_f32_fp8((int)v[r][j], true);
                acc[r][0] += lo[0]; acc[r][1] += lo[1];
                acc[r][2] += hi[0]; acc[r][3] += hi[1];
            }
    }
#pragma unroll
    for (int r = 0; r < 2; ++r)
#pragma unroll
        for (int k = 0; k < 4; ++k) acc[r][k] += __shfl_xor(acc[r][k], 32);
    if (a == 0) {
        int m2 = s >> 1;
        int a2 = (s & 1) << 6;
        float bb0 = b1[a2 + m2], bb1 = b1[a2 + 16 + m2];
        float bb2 = b1[a2 + 32 + m2], bb3 = b1[a2 + 48 + m2];
#pragma unroll
        for (int r = 0; r < 2; ++r) {
            if (r0 + r < n) {
                float nd = rsqrtf((float)max(e1[r] - e0[r], 1));
                float ns = norm_src[r0 + r];
                float f0 = fmaxf(fmaf(acc[r][0], nd, bb0), 0.f) * ns;
                float f1 = fmaxf(fmaf(acc[r][1], nd, bb1), 0.f) * ns;
                float f2 = fmaxf(fmaf(acc[r][2], nd, bb2), 0.f) * ns;
                float f3 = fmaxf(fmaf(acc[r][3], nd, bb3), 0.f) * ns;
                union { __hip_bfloat16 b; ushort u; } c0, c1, c2, c3;
                c0.b = __float2bfloat16(f0);
                c1.b = __float2bfloat16(f1);
                c2.b = __float2bfloat16(f2);
                c3.b = __float2bfloat16(f3);
                uint w0 = (uint)c0.u | ((uint)c1.u << 16);
                uint w1 = (uint)c2.u | ((uint)c3.u << 16);
                x2n[(size_t)(r0 + r) * 32 + s] = make_uint2(w0, w1);
            }
        }
    }
}

// ---- SpMM layer 2 + fused mean-pool: 4 dst rows per wave, fp8 gathers ---
// h2 row = 16 u32 (64B). lane: a=lane>>4 edge sub-idx, s=lane&15 slot.
// 16 gather loads in flight per wave (4 rows x 4). slot s byte c <-> feat 16c+s.
__launch_bounds__(256)
__global__ void spmm2_kernel(const uint* __restrict__ h2,
                             const int* __restrict__ row_start,
                             const int* __restrict__ csr_src,
                             const float* __restrict__ b2,
                             const int* __restrict__ gids,
                             const int* __restrict__ gcnt,
                             float* __restrict__ out, int n) {
    int wv = (blockIdx.x * blockDim.x + threadIdx.x) >> 6;
    int lane = threadIdx.x & 63;
    int wave = threadIdx.x >> 6;
    int r0 = wv * 4;
    int a = lane >> 4;
    int s = lane & 15;
    int e0[4], e1[4], g[4];
    float inv[4];
#pragma unroll
    for (int r = 0; r < 4; ++r) {
        int rr = min(r0 + r, n - 1);
        e0[r] = row_start[rr];
        e1[r] = row_start[rr + 1];
        g[r] = gids[rr];
        if (r0 + r >= n) { e1[r] = e0[r]; g[r] = -1; }
        inv[r] = 1.f / (float)max(gcnt[max(g[r], 0)], 1);
    }
    float acc[4][4] = {};
    int nb = 0;
#pragma unroll
    for (int r = 0; r < 4; ++r) nb = max(nb, (e1[r] - e0[r] + 15) >> 4);
    for (int b = 0; b < nb; ++b) {
        uint u[4][4];
#pragma unroll
        for (int r = 0; r < 4; ++r) {
            int base = e0[r] + b * 16;
            if (base < e1[r]) {  // wave-uniform
#pragma unroll
                for (int j = 0; j < 4; ++j) {
                    int idx = base + 4 * j + a;
                    int cidx = min(idx, e1[r] - 1);
                    uint vv = h2[(size_t)csr_src[cidx] * 16 + s];
                    u[r][j] = (idx < e1[r]) ? vv : 0u;
                }
            } else {
#pragma unroll
                for (int j = 0; j < 4; ++j) u[r][j] = 0u;
            }
        }
#pragma unroll
        for (int r = 0; r < 4; ++r)
#pragma unroll
            for (int j = 0; j < 4; ++j) {
                v2f lo = __builtin_amdgcn_cvt_pk_f32_fp8((int)u[r][j], false);
                v2f hi = __builtin_amdgcn_cvt_pk_f32_fp8((int)u[r][j], true);
                acc[r][0] += lo[0]; acc[r][1] += lo[1];
                acc[r][2] += hi[0]; acc[r][3] += hi[1];
            }
    }
#pragma unroll
    for (int r = 0; r < 4; ++r)
#pragma unroll
        for (int k = 0; k < 4; ++k) {
            acc[r][k] += __shfl_xor(acc[r][k], 16);
            acc[r][k] += __shfl_xor(acc[r][k], 32);
        }
    // per-row epilogue (all lanes hold full sums after reduce)
    float bb0 = b2[s], bb1 = b2[16 + s], bb2v = b2[32 + s], bb3 = b2[48 + s];
    float val[4][4];
#pragma unroll
    for (int r = 0; r < 4; ++r) {
        float nd = rsqrtf((float)max(e1[r] - e0[r], 1));
        bool vld = g[r] >= 0;
        val[r][0] = vld ? fmaxf(fmaf(acc[r][0], nd, bb0), 0.f) * inv[r] : 0.f;
        val[r][1] = vld ? fmaxf(fmaf(acc[r][1], nd, bb1), 0.f) * inv[r] : 0.f;
        val[r][2] = vld ? fmaxf(fmaf(acc[r][2], nd, bb2v), 0.f) * inv[r] : 0.f;
        val[r][3] = vld ? fmaxf(fmaf(acc[r][3], nd, bb3), 0.f) * inv[r] : 0.f;
    }
    __shared__ float sbuf[4][64];
    __shared__ int sg[4];
    bool same = (g[0] == g[1]) && (g[1] == g[2]) && (g[2] == g[3]) && (g[0] >= 0);
    int sgw;
    if (same) {
        if (a == 0) {
            sbuf[wave][s]      = val[0][0] + val[1][0] + val[2][0] + val[3][0];
            sbuf[wave][16 + s] = val[0][1] + val[1][1] + val[2][1] + val[3][1];
            sbuf[wave][32 + s] = val[0][2] + val[1][2] + val[2][2] + val[3][2];
            sbuf[wave][48 + s] = val[0][3] + val[1][3] + val[2][3] + val[3][3];
        }
        sgw = g[0];
    } else {
        if (a == 0) {
#pragma unroll
            for (int r = 0; r < 4; ++r) {
                if (g[r] >= 0) {
                    atomicAdd(&out[(size_t)g[r] * 64 + s], val[r][0]);
                    atomicAdd(&out[(size_t)g[r] * 64 + 16 + s], val[r][1]);
                    atomicAdd(&out[(size_t)g[r] * 64 + 32 + s], val[r][2]);
                    atomicAdd(&out[(size_t)g[r] * 64 + 48 + s], val[r][3]);
                }
            }
            sbuf[wave][s] = 0.f;
            sbuf[wave][16 + s] = 0.f;
            sbuf[wave][32 + s] = 0.f;
            sbuf[wave][48 + s] = 0.f;
        }
        sgw = -1;
    }
    if (lane == 0) sg[wave] = sgw;
    __syncthreads();
    if (wave == 0) {
        int g0 = sg[0], g1 = sg[1], g2 = sg[2], g3 = sg[3];
        if (g0 == g1 && g1 == g2 && g2 == g3 && g0 >= 0) {
            float ssum = sbuf[0][lane] + sbuf[1][lane] + sbuf[2][lane] + sbuf[3][lane];
            atomicAdd(&out[(size_t)g0 * 64 + lane], ssum);
        } else {
#pragma unroll
            for (int w = 0; w < 4; ++w)
                if (sg[w] >= 0)
                    atomicAdd(&out[(size_t)sg[w] * 64 + lane], sbuf[w][lane]);
        }
    }
}

extern "C" void kernel_launch(void* const* d_in, const int* in_sizes, int n_in,
                              void* d_out, int out_size, void* d_ws, size_t ws_size,
                              hipStream_t stream) {
    const float* features = (const float*)d_in[0];
    const float* W1 = (const float*)d_in[1];
    const float* b1 = (const float*)d_in[2];
    const float* W2 = (const float*)d_in[3];
    const float* b2 = (const float*)d_in[4];
    const int* src = (const int*)d_in[5];
    const int* dst = (const int*)d_in[6];
    const int* gids = (const int*)d_in[7];
    const int N = in_sizes[7];
    const int E = in_sizes[5];
    const int G = out_size / 64;  // out_size is FLOAT ELEMENTS: [G][64] f32
    float* out = (float*)d_out;
    const int P = (N + NPP - 1) >> NPP_SHIFT;

    char* ws = (char*)d_ws;
    size_t off = 0;
    auto alloc = [&](size_t bytes) -> void* {
        void* p = ws + off;
        off = (off + bytes + 255) & ~(size_t)255;
        return p;
    };
    int* counts = (int*)alloc((size_t)2 * NB * P * 4);
    int* offs = (int*)alloc((size_t)2 * NB * P * 4);
    int* ptot = (int*)alloc((size_t)2 * P * 4);
    int* pbase = (int*)alloc((size_t)2 * P * 4);
    int* gcnt = (int*)alloc((size_t)G * 4);
    int* ebuf_src = (int*)alloc((size_t)E * 4);
    int2* ebuf_dst = (int2*)alloc((size_t)E * 8);
    float* norm_src = (float*)alloc((size_t)N * 4);
    int* row_start = (int*)alloc((size_t)(N + 1) * 4);
    int* csr_src = (int*)alloc((size_t)E * 4);
    uint* h1 = (uint*)alloc((size_t)N * 128);                            // fp8 [N][128]
    __hip_bfloat16* x2n = (__hip_bfloat16*)alloc((size_t)N * 128 * 2);   // bf16, permuted
    uint* h2 = h1;  // fp8 [N][64] (64B rows); h1 dead after spmm1

    hipMemsetAsync(out, 0, (size_t)out_size * sizeof(float), stream);
    hipMemsetAsync(gcnt, 0, (size_t)G * 4, stream);

    // --- atomic-free graph build + per-graph node counts ---
    passA_count<<<NB, 256, 0, stream>>>(src, dst, E, P, counts, counts + (size_t)NB * P,
                                        gids, N, G, gcnt);
    scanB<<<2 * P, 1024, 0, stream>>>(counts, offs, ptot, P);
    passC_scatter<<<NB, 256, 0, stream>>>(src, dst, E, P, offs, ptot, pbase,
                                          ebuf_src, ebuf_dst);
    passD_build<<<P, 512, 0, stream>>>(ebuf_src, ebuf_dst, ptot, pbase, norm_src, row_start,
                                       csr_src, N, E, P);

    // Layer 1: h1(fp8, permuted) = (features * norm_src) @ W1
    gemm_mfma<128, false, false, true><<<768, 256, 0, stream>>>(features, W1, norm_src,
                                                                (void*)h1, N);
    // SpMM 1: 2 rows/wave
    {
        int waves = (N + 1) / 2;
        int blocks = (waves * 64 + 255) / 256;
        spmm1_kernel<<<blocks, 256, 0, stream>>>(h1, row_start, csr_src, b1, norm_src,
                                                 (uint2*)x2n, N);
    }
    // Layer 2: h2(fp8, 64B rows) = x2n(permuted) @ W2  (W rows permuted to match)
    gemm_mfma<64, true, true, true><<<768, 256, 0, stream>>>(x2n, W2, nullptr,
                                                             (void*)h2, N);
    // SpMM 2 + fused mean-pool: 4 rows/wave
    {
        int waves = (N + 3) / 4;
        int blocks = (waves * 64 + 255) / 256;
        spmm2_kernel<<<blocks, 256, 0, stream>>>(h2, row_start, csr_src, b2,
                                                 gids, gcnt, out, N);
    }
}